// Round 8
// baseline (562.910 us; speedup 1.0000x reference)
//
#include <hip/hip_runtime.h>

#define BB    64
#define TT    256
#define EMBD  300
#define HIDD  512
#define OUTC  10
#define THETA 10.0
#define FUTN  12     // >= Kr-1 (Kr expected 11)
#define KSMAX 80     // >= Ks (expected 77), srm zero-padded
#define GT    32     // gemm t-tile
#define GE    8      // gemm e-chunk
#define WGRP  9      // doubles per 8-channel w group (8 + 1 pad)
#define WROW  (64 * WGRP)   // 576 doubles per e-row
#define HSTR  33     // firscan LDS h row stride (doubles), [t][c]

// ---------------- tiny: W2 f32 -> f64 ---------------------------------------
__global__ __launch_bounds__(256)
void w2cvt_kernel(const float* __restrict__ W2, double* __restrict__ w2d)
{
    const int k = blockIdx.x * 256 + threadIdx.x;
    if (k < OUTC * HIDD) w2d[k] = (double)W2[k];
}

// ------- gemm1: m1[b][t][c] = sum_e W1[c][e] * emb[feed[b][t]][e] -----------
__global__ __launch_bounds__(512)
void gemm1_kernel(const int* __restrict__ feed, const float* __restrict__ emb,
                  const float* __restrict__ W1, double* __restrict__ m1)
{
    __shared__ double wl[GE * WROW];    // [e][c-groups of 8 + pad] 36.9 KB
    __shared__ double xs[GE][GT + 1];   // [e][t] 2.1 KB
    __shared__ int    idxb[GT];

    const int tid = threadIdx.x;
    const int t0  = blockIdx.x * GT;
    const int b   = blockIdx.y;

    if (tid < GT) idxb[tid] = feed[b * TT + t0 + tid];
    __syncthreads();

    const int cg = tid & 63;   // c = 8*cg + j
    const int tg = tid >> 6;   // t = t0 + 4*tg + i

    double acc[4][8];
#pragma unroll
    for (int i = 0; i < 4; ++i)
#pragma unroll
        for (int j = 0; j < 8; ++j) acc[i][j] = 0.0;

    const int NCH = (EMBD + GE - 1) / GE;   // 38 (last chunk zero-padded)
    for (int ch = 0; ch < NCH; ++ch) {
        const int e0 = ch * GE;
        // stage w: thread c reads W1[c][e0..e0+7] (row base 1200B, e0*4 mult of 32 -> aligned)
        {
            const int c = tid;
            float4 wa = make_float4(0.f, 0.f, 0.f, 0.f);
            float4 wb = make_float4(0.f, 0.f, 0.f, 0.f);
            if (e0 < EMBD)     wa = *(const float4*)&W1[(size_t)c * EMBD + e0];
            if (e0 + 4 < EMBD) wb = *(const float4*)&W1[(size_t)c * EMBD + e0 + 4];
            const int g = (c >> 3) * WGRP + (c & 7);
            wl[0 * WROW + g] = (double)wa.x;
            wl[1 * WROW + g] = (double)wa.y;
            wl[2 * WROW + g] = (double)wa.z;
            wl[3 * WROW + g] = (double)wa.w;
            wl[4 * WROW + g] = (double)wb.x;
            wl[5 * WROW + g] = (double)wb.y;
            wl[6 * WROW + g] = (double)wb.z;
            wl[7 * WROW + g] = (double)wb.w;
        }
        // stage x: 256 threads, t = tid>>3, e = tid&7
        if (tid < 256) {
            const int t = tid >> 3, e = tid & 7;
            const float v = (e0 + e < EMBD)
                ? emb[(size_t)idxb[t] * EMBD + e0 + e] : 0.f;
            xs[e][t] = (double)v;
        }
        __syncthreads();

#pragma unroll
        for (int e = 0; e < GE; ++e) {
            const double* wp = &wl[e * WROW + cg * WGRP];
            const double w0 = wp[0], w1 = wp[1], w2 = wp[2], w3 = wp[3];
            const double w4 = wp[4], w5 = wp[5], w6 = wp[6], w7 = wp[7];
            const double x0 = xs[e][4 * tg + 0];
            const double x1 = xs[e][4 * tg + 1];
            const double x2 = xs[e][4 * tg + 2];
            const double x3 = xs[e][4 * tg + 3];
            acc[0][0] = fma(x0, w0, acc[0][0]); acc[0][1] = fma(x0, w1, acc[0][1]);
            acc[0][2] = fma(x0, w2, acc[0][2]); acc[0][3] = fma(x0, w3, acc[0][3]);
            acc[0][4] = fma(x0, w4, acc[0][4]); acc[0][5] = fma(x0, w5, acc[0][5]);
            acc[0][6] = fma(x0, w6, acc[0][6]); acc[0][7] = fma(x0, w7, acc[0][7]);
            acc[1][0] = fma(x1, w0, acc[1][0]); acc[1][1] = fma(x1, w1, acc[1][1]);
            acc[1][2] = fma(x1, w2, acc[1][2]); acc[1][3] = fma(x1, w3, acc[1][3]);
            acc[1][4] = fma(x1, w4, acc[1][4]); acc[1][5] = fma(x1, w5, acc[1][5]);
            acc[1][6] = fma(x1, w6, acc[1][6]); acc[1][7] = fma(x1, w7, acc[1][7]);
            acc[2][0] = fma(x2, w0, acc[2][0]); acc[2][1] = fma(x2, w1, acc[2][1]);
            acc[2][2] = fma(x2, w2, acc[2][2]); acc[2][3] = fma(x2, w3, acc[2][3]);
            acc[2][4] = fma(x2, w4, acc[2][4]); acc[2][5] = fma(x2, w5, acc[2][5]);
            acc[2][6] = fma(x2, w6, acc[2][6]); acc[2][7] = fma(x2, w7, acc[2][7]);
            acc[3][0] = fma(x3, w0, acc[3][0]); acc[3][1] = fma(x3, w1, acc[3][1]);
            acc[3][2] = fma(x3, w2, acc[3][2]); acc[3][3] = fma(x3, w3, acc[3][3]);
            acc[3][4] = fma(x3, w4, acc[3][4]); acc[3][5] = fma(x3, w5, acc[3][5]);
            acc[3][6] = fma(x3, w6, acc[3][6]); acc[3][7] = fma(x3, w7, acc[3][7]);
        }
        __syncthreads();
    }

    // write m1[b][t][c]: lanes cg consecutive -> 4 KB contiguous per instr
#pragma unroll
    for (int i = 0; i < 4; ++i) {
        double* dst = &m1[((size_t)b * TT + t0 + 4 * tg + i) * HIDD + 8 * cg];
        *(double2*)(dst + 0) = make_double2(acc[i][0], acc[i][1]);
        *(double2*)(dst + 2) = make_double2(acc[i][2], acc[i][3]);
        *(double2*)(dst + 4) = make_double2(acc[i][4], acc[i][5]);
        *(double2*)(dst + 6) = make_double2(acc[i][6], acc[i][7]);
    }
}

// ------- firscan: psp FIR + spike scan per (b, 32c); m1 is [b][t][c] --------
__global__ __launch_bounds__(512)
void firscan_kernel(const double* __restrict__ m1, const float* __restrict__ srm,
                    const float* __restrict__ refk, unsigned char* __restrict__ s1,
                    int Ks, int Kr)
{
    __shared__ double        h[TT * HSTR];   // [t][c] 67.6 KB
    __shared__ unsigned char sb[32 * 260];   // spikes, stride 260
    __shared__ double        srm_sm[KSMAX];

    const int tid = threadIdx.x;
    const int c0  = blockIdx.x * 32;
    const int b   = blockIdx.y;

    if (tid < KSMAX) srm_sm[tid] = (tid < Ks) ? (double)srm[tid] : 0.0;

    // stage: coalesced 256B rows
    for (int u = tid; u < TT * 32; u += 512) {
        const int t = u >> 5, c = u & 31;
        h[t * HSTR + c] = m1[((size_t)b * TT + t) * HIDD + c0 + c];
    }
    __syncthreads();

    // FIR: thread (c=tid&31, tb=tid>>5 of 16), two passes of 8 outputs,
    // j ascending 0..KSMAX-1 -> bit-identical to prior rounds
    const int c  = tid & 31, tb = tid >> 5;
    const int tf = tb * 16;
    double pout[16];
#pragma unroll
    for (int k = 0; k < 16; ++k) pout[k] = 0.0;
#pragma unroll
    for (int pp = 0; pp < 2; ++pp) {
        const int tq = tf + pp * 8;
        double win[8];
#pragma unroll
        for (int k = 0; k < 8; ++k) win[k] = h[(tq + k) * HSTR + c];
        for (int jb = 0; jb < KSMAX; jb += 8) {
#pragma unroll
            for (int jj = 0; jj < 8; ++jj) {
                const double sj = srm_sm[jb + jj];
#pragma unroll
                for (int i = 0; i < 8; ++i)
                    pout[pp * 8 + i] = fma(win[(8 + i - jj) & 7], sj, pout[pp * 8 + i]);
                const int idx = tq - (jb + jj) - 1;
                win[(7 - jj) & 7] = (idx >= 0) ? h[idx * HSTR + c] : 0.0;
            }
        }
    }
    __syncthreads();                 // all FIR reads done before overwrite
#pragma unroll
    for (int k = 0; k < 16; ++k)
        h[(tf + k) * HSTR + c] = pout[k];
    __syncthreads();

    // spike scan: 32 lanes, one per channel, next-u prefetch
    if (tid < 32) {
        double fut[FUTN], rsh[FUTN];
#pragma unroll
        for (int i = 0; i < FUTN; ++i) {
            fut[i] = (i + 1 < Kr) ? (double)refk[i + 1] : 0.0;
            rsh[i] = 0.0;
        }
        unsigned char* sr = &sb[tid * 260];
        double un = h[0 * HSTR + tid];
        for (int t = 0; t < TT; ++t) {
            const double uc = un;
            un = (t < TT - 1) ? h[(t + 1) * HSTR + tid] : 0.0;
            const double m  = uc + rsh[0];
            const double sv = (m >= THETA) ? 1.0 : 0.0;
#pragma unroll
            for (int i = 0; i < FUTN - 1; ++i) rsh[i] = fma(sv, fut[i], rsh[i + 1]);
            rsh[FUTN - 1] = sv * fut[FUTN - 1];
            sr[t] = (unsigned char)(sv != 0.0 ? 1 : 0);
        }
    }
    __syncthreads();

    // spikes -> global s1[b][c][t] (uchar via uint, coalesced)
    for (int u = tid; u < 32 * (TT / 4); u += 512) {
        const int cc = u >> 6, tw = u & 63;
        const unsigned int v = *(const unsigned int*)&sb[cc * 260 + 4 * tw];
        *(unsigned int*)&s1[((size_t)b * HIDD + c0 + cc) * TT + 4 * tw] = v;
    }
}

// ---------------- layer 2a: m2 = W2 . s1 (f64), parallel over b x t ---------
__global__ __launch_bounds__(256, 2)
void layer2a_kernel(const unsigned char* __restrict__ s1,
                    const double* __restrict__ w2d, double* __restrict__ m2)
{
    __shared__ double w2l[OUTC * HIDD];    // 40 KB
    __shared__ double red[4][OUTC][65];    // 20.8 KB

    const int tid = threadIdx.x;
    const int b = blockIdx.x, q = blockIdx.y;
    const int tl = tid & 63, hq = tid >> 6;
    const int t  = q * 64 + tl;

    for (int u = tid; u < OUTC * HIDD; u += 256) w2l[u] = w2d[u];
    __syncthreads();

    double p[OUTC];
#pragma unroll
    for (int oc = 0; oc < OUTC; ++oc) p[oc] = 0.0;

    const unsigned char* sp = s1 + ((size_t)b * HIDD + hq * 128) * TT + t;
    for (int h0 = 0; h0 < 128; ++h0) {
        const double sv = (double)sp[(size_t)h0 * TT];
        const int hh = hq * 128 + h0;
#pragma unroll
        for (int oc = 0; oc < OUTC; ++oc)
            p[oc] = fma(sv, w2l[oc * HIDD + hh], p[oc]);
    }
#pragma unroll
    for (int oc = 0; oc < OUTC; ++oc) red[hq][oc][tl] = p[oc];
    __syncthreads();

    for (int u = tid; u < OUTC * 64; u += 256) {
        const int oc = u >> 6, t2 = u & 63;
        const double s = ((red[0][oc][t2] + red[1][oc][t2]) +
                          red[2][oc][t2]) + red[3][oc][t2];
        m2[((size_t)b * OUTC + oc) * TT + q * 64 + t2] = s;
    }
}

// ---------------- layer 2b: FIR + spike scan on m2 --------------------------
__global__ __launch_bounds__(256)
void layer2b_kernel(const double* __restrict__ m2, const float* __restrict__ srm,
                    const float* __restrict__ refk, float* __restrict__ out,
                    int Ks, int Kr)
{
    __shared__ double mh[OUTC][257];
    __shared__ double uh[OUTC][257];
    __shared__ double srm_sm[KSMAX];
    __shared__ unsigned char s2[OUTC][260];

    const int tid = threadIdx.x;       // == t
    const int b   = blockIdx.x;

    if (tid < KSMAX) srm_sm[tid] = (tid < Ks) ? (double)srm[tid] : 0.0;
    for (int u = tid; u < OUTC * TT; u += 256)
        mh[u >> 8][u & 255] = m2[(size_t)b * OUTC * TT + u];
    __syncthreads();

    double p[OUTC];
#pragma unroll
    for (int oc = 0; oc < OUTC; ++oc) p[oc] = 0.0;
    for (int j = 0; j < KSMAX; ++j) {
        const int idx = tid - j;
        if (idx >= 0) {
            const double sj = srm_sm[j];
#pragma unroll
            for (int oc = 0; oc < OUTC; ++oc)
                p[oc] = fma(mh[oc][idx], sj, p[oc]);
        }
    }
#pragma unroll
    for (int oc = 0; oc < OUTC; ++oc) uh[oc][tid] = p[oc];
    __syncthreads();

    if (tid < OUTC) {
        double fut[FUTN], rsh[FUTN];
#pragma unroll
        for (int i = 0; i < FUTN; ++i) {
            fut[i] = (i + 1 < Kr) ? (double)refk[i + 1] : 0.0;
            rsh[i] = 0.0;
        }
        for (int t = 0; t < TT; ++t) {
            const double m  = uh[tid][t] + rsh[0];
            const double sv = (m >= THETA) ? 1.0 : 0.0;
#pragma unroll
            for (int i = 0; i < FUTN - 1; ++i) rsh[i] = fma(sv, fut[i], rsh[i + 1]);
            rsh[FUTN - 1] = sv * fut[FUTN - 1];
            s2[tid][t] = (unsigned char)(sv != 0.0 ? 1 : 0);
        }
    }
    __syncthreads();

    for (int u = tid; u < OUTC * TT; u += 256)
        out[(size_t)b * OUTC * TT + u] = (float)s2[u >> 8][u & 255];
}

extern "C" void kernel_launch(void* const* d_in, const int* in_sizes, int n_in,
                              void* d_out, int out_size, void* d_ws, size_t ws_size,
                              hipStream_t stream)
{
    const int*   feed = (const int*)  d_in[0];
    const float* emb  = (const float*)d_in[1];
    const float* W1   = (const float*)d_in[2];
    const float* W2   = (const float*)d_in[3];
    const float* srm  = (const float*)d_in[4];
    const float* refk = (const float*)d_in[5];
    const int Ks = in_sizes[4];
    const int Kr = in_sizes[5];

    // ws layout identical footprint to round 7 (proven to fit):
    // [s1 8,388,608][w2d 40,960][m2 1,310,720][m1 67,108,864]
    const size_t S1B  = (size_t)BB * HIDD * TT;
    const size_t W2DB = (size_t)OUTC * HIDD * 8;
    const size_t M2B  = (size_t)BB * OUTC * TT * 8;
    unsigned char* s1c = (unsigned char*)d_ws;
    double* w2d = (double*)((char*)d_ws + S1B);
    double* m2  = (double*)((char*)d_ws + S1B + W2DB);
    double* m1  = (double*)((char*)d_ws + S1B + W2DB + M2B);
    float*  out = (float*)d_out;

    w2cvt_kernel  <<<dim3(20),           256, 0, stream>>>(W2, w2d);
    gemm1_kernel  <<<dim3(TT / GT, BB),  512, 0, stream>>>(feed, emb, W1, m1);
    firscan_kernel<<<dim3(HIDD / 32, BB),512, 0, stream>>>(m1, srm, refk, s1c, Ks, Kr);
    layer2a_kernel<<<dim3(BB, 4),        256, 0, stream>>>(s1c, w2d, m2);
    layer2b_kernel<<<dim3(BB),           256, 0, stream>>>(m2, srm, refk, out, Ks, Kr);
}

// Round 9
// 443.020 us; speedup vs baseline: 1.2706x; 1.2706x over previous
//
#include <hip/hip_runtime.h>

#define BB    64
#define TT    256
#define EMBD  300
#define HIDD  512
#define OUTC  10
#define THETA 10.0
#define FUTN  12     // >= Kr-1 (Kr expected 11)
#define KSMAX 80     // >= Ks (expected 77), srm zero-padded
#define GT    32     // gemm t-tile
#define GE    8      // gemm e-chunk
#define WGRP  9      // doubles per 8-channel w group (8 + 1 pad)
#define WROW  (64 * WGRP)   // 576 doubles per e-row
#define HSTRD 258    // firscan LDS h row stride (doubles), [c][t]

// ---------------- tiny: W2 f32 -> f64 ---------------------------------------
__global__ __launch_bounds__(256)
void w2cvt_kernel(const float* __restrict__ W2, double* __restrict__ w2d)
{
    const int k = blockIdx.x * 256 + threadIdx.x;
    if (k < OUTC * HIDD) w2d[k] = (double)W2[k];
}

// ------- gemm1: m1[b][t][c] = sum_e W1[c][e] * emb[feed[b][t]][e] -----------
__global__ __launch_bounds__(512)
void gemm1_kernel(const int* __restrict__ feed, const float* __restrict__ emb,
                  const float* __restrict__ W1, double* __restrict__ m1)
{
    __shared__ double wl[GE * WROW];    // [e][c-groups of 8 + pad] 36.9 KB
    __shared__ double xs[GE][GT + 1];   // [e][t] 2.1 KB
    __shared__ int    idxb[GT];

    const int tid = threadIdx.x;
    const int t0  = blockIdx.x * GT;
    const int b   = blockIdx.y;

    if (tid < GT) idxb[tid] = feed[b * TT + t0 + tid];
    __syncthreads();

    const int cg = tid & 63;   // c = 8*cg + j
    const int tg = tid >> 6;   // t = t0 + 4*tg + i

    double acc[4][8];
#pragma unroll
    for (int i = 0; i < 4; ++i)
#pragma unroll
        for (int j = 0; j < 8; ++j) acc[i][j] = 0.0;

    const int NCH = (EMBD + GE - 1) / GE;   // 38 (last chunk zero-padded)
    for (int ch = 0; ch < NCH; ++ch) {
        const int e0 = ch * GE;
        // stage w: thread c reads W1[c][e0..e0+7]
        {
            const int c = tid;
            float4 wa = make_float4(0.f, 0.f, 0.f, 0.f);
            float4 wb = make_float4(0.f, 0.f, 0.f, 0.f);
            if (e0 < EMBD)     wa = *(const float4*)&W1[(size_t)c * EMBD + e0];
            if (e0 + 4 < EMBD) wb = *(const float4*)&W1[(size_t)c * EMBD + e0 + 4];
            const int g = (c >> 3) * WGRP + (c & 7);
            wl[0 * WROW + g] = (double)wa.x;
            wl[1 * WROW + g] = (double)wa.y;
            wl[2 * WROW + g] = (double)wa.z;
            wl[3 * WROW + g] = (double)wa.w;
            wl[4 * WROW + g] = (double)wb.x;
            wl[5 * WROW + g] = (double)wb.y;
            wl[6 * WROW + g] = (double)wb.z;
            wl[7 * WROW + g] = (double)wb.w;
        }
        // stage x: 256 threads, t = tid>>3, e = tid&7
        if (tid < 256) {
            const int t = tid >> 3, e = tid & 7;
            const float v = (e0 + e < EMBD)
                ? emb[(size_t)idxb[t] * EMBD + e0 + e] : 0.f;
            xs[e][t] = (double)v;
        }
        __syncthreads();

#pragma unroll
        for (int e = 0; e < GE; ++e) {
            const double* wp = &wl[e * WROW + cg * WGRP];
            const double w0 = wp[0], w1 = wp[1], w2 = wp[2], w3 = wp[3];
            const double w4 = wp[4], w5 = wp[5], w6 = wp[6], w7 = wp[7];
            const double x0 = xs[e][4 * tg + 0];
            const double x1 = xs[e][4 * tg + 1];
            const double x2 = xs[e][4 * tg + 2];
            const double x3 = xs[e][4 * tg + 3];
            acc[0][0] = fma(x0, w0, acc[0][0]); acc[0][1] = fma(x0, w1, acc[0][1]);
            acc[0][2] = fma(x0, w2, acc[0][2]); acc[0][3] = fma(x0, w3, acc[0][3]);
            acc[0][4] = fma(x0, w4, acc[0][4]); acc[0][5] = fma(x0, w5, acc[0][5]);
            acc[0][6] = fma(x0, w6, acc[0][6]); acc[0][7] = fma(x0, w7, acc[0][7]);
            acc[1][0] = fma(x1, w0, acc[1][0]); acc[1][1] = fma(x1, w1, acc[1][1]);
            acc[1][2] = fma(x1, w2, acc[1][2]); acc[1][3] = fma(x1, w3, acc[1][3]);
            acc[1][4] = fma(x1, w4, acc[1][4]); acc[1][5] = fma(x1, w5, acc[1][5]);
            acc[1][6] = fma(x1, w6, acc[1][6]); acc[1][7] = fma(x1, w7, acc[1][7]);
            acc[2][0] = fma(x2, w0, acc[2][0]); acc[2][1] = fma(x2, w1, acc[2][1]);
            acc[2][2] = fma(x2, w2, acc[2][2]); acc[2][3] = fma(x2, w3, acc[2][3]);
            acc[2][4] = fma(x2, w4, acc[2][4]); acc[2][5] = fma(x2, w5, acc[2][5]);
            acc[2][6] = fma(x2, w6, acc[2][6]); acc[2][7] = fma(x2, w7, acc[2][7]);
            acc[3][0] = fma(x3, w0, acc[3][0]); acc[3][1] = fma(x3, w1, acc[3][1]);
            acc[3][2] = fma(x3, w2, acc[3][2]); acc[3][3] = fma(x3, w3, acc[3][3]);
            acc[3][4] = fma(x3, w4, acc[3][4]); acc[3][5] = fma(x3, w5, acc[3][5]);
            acc[3][6] = fma(x3, w6, acc[3][6]); acc[3][7] = fma(x3, w7, acc[3][7]);
        }
        __syncthreads();
    }

    // write m1[b][t][c]
#pragma unroll
    for (int i = 0; i < 4; ++i) {
        double* dst = &m1[((size_t)b * TT + t0 + 4 * tg + i) * HIDD + 8 * cg];
        *(double2*)(dst + 0) = make_double2(acc[i][0], acc[i][1]);
        *(double2*)(dst + 2) = make_double2(acc[i][2], acc[i][3]);
        *(double2*)(dst + 4) = make_double2(acc[i][4], acc[i][5]);
        *(double2*)(dst + 6) = make_double2(acc[i][6], acc[i][7]);
    }
}

// ------- firscan: psp FIR + spike scan per (b, 16c); m1 is [b][t][c] --------
__global__ __launch_bounds__(256)
void firscan_kernel(const double* __restrict__ m1, const float* __restrict__ srm,
                    const float* __restrict__ refk, unsigned char* __restrict__ s1,
                    int Ks, int Kr)
{
    __shared__ double        h[16 * HSTRD];   // [c][t] 33.0 KB
    __shared__ unsigned char sb[16 * 260];    // spikes, stride 260
    __shared__ double        srm_sm[KSMAX];

    const int tid = threadIdx.x;
    const int c0  = blockIdx.x * 16;
    const int b   = blockIdx.y;

    if (tid < KSMAX) srm_sm[tid] = (tid < Ks) ? (double)srm[tid] : 0.0;

    // stage: m1[b][t][c0..c0+15] -> h[c][t]  (reads coalesced over c)
    for (int u = tid; u < 16 * TT; u += 256) {
        const int c = u & 15, t = u >> 4;
        h[c * HSTRD + t] = m1[((size_t)b * TT + t) * HIDD + c0 + c];
    }
    __syncthreads();

    // FIR: thread (c=tid&15, tb=tid>>4), 16 outputs t = tb*16 + i.
    // 3-bank register window HI/MID/LO, next-LO loaded one block ahead.
    // j ascending 0..KSMAX-1 -> bit-identical to prior rounds.
    const int cf = tid & 15, tb = tid >> 4;
    const int t0 = tb * 16;
    const double* hrow = &h[cf * HSTRD];

    double pout[16];
#pragma unroll
    for (int k = 0; k < 16; ++k) pout[k] = 0.0;

    double HI[8], MID[8], LO[8];
#pragma unroll
    for (int k = 0; k < 8; ++k) {
        HI[k]  = hrow[t0 + 8 + k];
        MID[k] = hrow[t0 + k];
        const int idx = t0 - 8 + k;
        LO[k] = (idx >= 0) ? hrow[idx] : 0.0;
    }

#pragma unroll
    for (int jb = 0; jb < KSMAX; jb += 8) {
        double NEW[8];
        if (jb + 8 < KSMAX) {
#pragma unroll
            for (int k = 0; k < 8; ++k) {
                const int idx = t0 - jb - 16 + k;
                NEW[k] = (idx >= 0) ? hrow[idx] : 0.0;
            }
        }
#pragma unroll
        for (int jj = 0; jj < 8; ++jj) {
            const double sj = srm_sm[jb + jj];
#pragma unroll
            for (int i = 0; i < 16; ++i) {
                const int d = i - jj;    // compile-time after unroll
                const double hv = (d >= 8) ? HI[(d - 8) & 7]
                               : (d >= 0) ? MID[d & 7]
                                          : LO[(8 + d) & 7];
                pout[i] = fma(hv, sj, pout[i]);
            }
        }
        if (jb + 8 < KSMAX) {
#pragma unroll
            for (int k = 0; k < 8; ++k) { HI[k] = MID[k]; MID[k] = LO[k]; LO[k] = NEW[k]; }
        }
    }
    __syncthreads();                 // all FIR reads done before overwrite
#pragma unroll
    for (int k = 0; k < 16; ++k)
        h[cf * HSTRD + t0 + k] = pout[k];
    __syncthreads();

    // spike scan: 16 lanes, one per channel, next-u prefetch
    if (tid < 16) {
        double fut[FUTN], rsh[FUTN];
#pragma unroll
        for (int i = 0; i < FUTN; ++i) {
            fut[i] = (i + 1 < Kr) ? (double)refk[i + 1] : 0.0;
            rsh[i] = 0.0;
        }
        const double*  hr = &h[tid * HSTRD];
        unsigned char* sr = &sb[tid * 260];
        double un = hr[0];
        for (int t = 0; t < TT; ++t) {
            const double uc = un;
            un = (t < TT - 1) ? hr[t + 1] : 0.0;
            const double m  = uc + rsh[0];
            const double sv = (m >= THETA) ? 1.0 : 0.0;
#pragma unroll
            for (int i = 0; i < FUTN - 1; ++i) rsh[i] = fma(sv, fut[i], rsh[i + 1]);
            rsh[FUTN - 1] = sv * fut[FUTN - 1];
            sr[t] = (unsigned char)(sv != 0.0 ? 1 : 0);
        }
    }
    __syncthreads();

    // spikes -> global s1[b][c][t] (uchar via uint, coalesced)
    {
        const int tl2 = tid & 63;
#pragma unroll
        for (int r = 0; r < 4; ++r) {
            const int c = (tid >> 6) + 4 * r;
            const unsigned int v = *(const unsigned int*)&sb[c * 260 + 4 * tl2];
            *(unsigned int*)&s1[((size_t)b * HIDD + c0 + c) * TT + 4 * tl2] = v;
        }
    }
}

// ---------------- layer 2a: m2 = W2 . s1 (f64), parallel over b x t ---------
__global__ __launch_bounds__(256, 2)
void layer2a_kernel(const unsigned char* __restrict__ s1,
                    const double* __restrict__ w2d, double* __restrict__ m2)
{
    __shared__ double w2l[OUTC * HIDD];    // 40 KB
    __shared__ double red[4][OUTC][65];    // 20.8 KB

    const int tid = threadIdx.x;
    const int b = blockIdx.x, q = blockIdx.y;
    const int tl = tid & 63, hq = tid >> 6;
    const int t  = q * 64 + tl;

    for (int u = tid; u < OUTC * HIDD; u += 256) w2l[u] = w2d[u];
    __syncthreads();

    double p[OUTC];
#pragma unroll
    for (int oc = 0; oc < OUTC; ++oc) p[oc] = 0.0;

    const unsigned char* sp = s1 + ((size_t)b * HIDD + hq * 128) * TT + t;
    for (int h0 = 0; h0 < 128; ++h0) {
        const double sv = (double)sp[(size_t)h0 * TT];
        const int hh = hq * 128 + h0;
#pragma unroll
        for (int oc = 0; oc < OUTC; ++oc)
            p[oc] = fma(sv, w2l[oc * HIDD + hh], p[oc]);
    }
#pragma unroll
    for (int oc = 0; oc < OUTC; ++oc) red[hq][oc][tl] = p[oc];
    __syncthreads();

    for (int u = tid; u < OUTC * 64; u += 256) {
        const int oc = u >> 6, t2 = u & 63;
        const double s = ((red[0][oc][t2] + red[1][oc][t2]) +
                          red[2][oc][t2]) + red[3][oc][t2];
        m2[((size_t)b * OUTC + oc) * TT + q * 64 + t2] = s;
    }
}

// ---------------- layer 2b: FIR + spike scan on m2 --------------------------
__global__ __launch_bounds__(256)
void layer2b_kernel(const double* __restrict__ m2, const float* __restrict__ srm,
                    const float* __restrict__ refk, float* __restrict__ out,
                    int Ks, int Kr)
{
    __shared__ double mh[OUTC][257];
    __shared__ double uh[OUTC][257];
    __shared__ double srm_sm[KSMAX];
    __shared__ unsigned char s2[OUTC][260];

    const int tid = threadIdx.x;       // == t
    const int b   = blockIdx.x;

    if (tid < KSMAX) srm_sm[tid] = (tid < Ks) ? (double)srm[tid] : 0.0;
    for (int u = tid; u < OUTC * TT; u += 256)
        mh[u >> 8][u & 255] = m2[(size_t)b * OUTC * TT + u];
    __syncthreads();

    double p[OUTC];
#pragma unroll
    for (int oc = 0; oc < OUTC; ++oc) p[oc] = 0.0;
    for (int j = 0; j < KSMAX; ++j) {
        const int idx = tid - j;
        if (idx >= 0) {
            const double sj = srm_sm[j];
#pragma unroll
            for (int oc = 0; oc < OUTC; ++oc)
                p[oc] = fma(mh[oc][idx], sj, p[oc]);
        }
    }
#pragma unroll
    for (int oc = 0; oc < OUTC; ++oc) uh[oc][tid] = p[oc];
    __syncthreads();

    if (tid < OUTC) {
        double fut[FUTN], rsh[FUTN];
#pragma unroll
        for (int i = 0; i < FUTN; ++i) {
            fut[i] = (i + 1 < Kr) ? (double)refk[i + 1] : 0.0;
            rsh[i] = 0.0;
        }
        for (int t = 0; t < TT; ++t) {
            const double m  = uh[tid][t] + rsh[0];
            const double sv = (m >= THETA) ? 1.0 : 0.0;
#pragma unroll
            for (int i = 0; i < FUTN - 1; ++i) rsh[i] = fma(sv, fut[i], rsh[i + 1]);
            rsh[FUTN - 1] = sv * fut[FUTN - 1];
            s2[tid][t] = (unsigned char)(sv != 0.0 ? 1 : 0);
        }
    }
    __syncthreads();

    for (int u = tid; u < OUTC * TT; u += 256)
        out[(size_t)b * OUTC * TT + u] = (float)s2[u >> 8][u & 255];
}

extern "C" void kernel_launch(void* const* d_in, const int* in_sizes, int n_in,
                              void* d_out, int out_size, void* d_ws, size_t ws_size,
                              hipStream_t stream)
{
    const int*   feed = (const int*)  d_in[0];
    const float* emb  = (const float*)d_in[1];
    const float* W1   = (const float*)d_in[2];
    const float* W2   = (const float*)d_in[3];
    const float* srm  = (const float*)d_in[4];
    const float* refk = (const float*)d_in[5];
    const int Ks = in_sizes[4];
    const int Kr = in_sizes[5];

    // ws layout (proven): [s1 8,388,608][w2d 40,960][m2 1,310,720][m1 67,108,864]
    const size_t S1B  = (size_t)BB * HIDD * TT;
    const size_t W2DB = (size_t)OUTC * HIDD * 8;
    const size_t M2B  = (size_t)BB * OUTC * TT * 8;
    unsigned char* s1c = (unsigned char*)d_ws;
    double* w2d = (double*)((char*)d_ws + S1B);
    double* m2  = (double*)((char*)d_ws + S1B + W2DB);
    double* m1  = (double*)((char*)d_ws + S1B + W2DB + M2B);
    float*  out = (float*)d_out;

    w2cvt_kernel  <<<dim3(20),            256, 0, stream>>>(W2, w2d);
    gemm1_kernel  <<<dim3(TT / GT, BB),   512, 0, stream>>>(feed, emb, W1, m1);
    firscan_kernel<<<dim3(HIDD / 16, BB), 256, 0, stream>>>(m1, srm, refk, s1c, Ks, Kr);
    layer2a_kernel<<<dim3(BB, 4),         256, 0, stream>>>(s1c, w2d, m2);
    layer2b_kernel<<<dim3(BB),            256, 0, stream>>>(m2, srm, refk, out, Ks, Kr);
}

// Round 10
// 396.484 us; speedup vs baseline: 1.4198x; 1.1174x over previous
//
#include <hip/hip_runtime.h>

#define BB    64
#define TT    256
#define EMBD  300
#define HIDD  512
#define OUTC  10
#define THETA 10.0
#define FUTN  12     // >= Kr-1 (Kr expected 11)
#define KSMAX 80     // >= Ks (expected 77), srm zero-padded
#define GT    32     // gemm t-tile
#define GC    256    // gemm c-tile
#define GE    8      // gemm e-chunk
#define WGRP  9      // doubles per 8-channel w group (8 + 1 pad)
#define WROW  (32 * WGRP)   // 288 doubles per e-row (32 groups)
#define HSTRD 258    // firscan LDS h row stride (doubles), [c][t]

// ---------------- tiny: W2 f32 -> f64 ---------------------------------------
__global__ __launch_bounds__(256)
void w2cvt_kernel(const float* __restrict__ W2, double* __restrict__ w2d)
{
    const int k = blockIdx.x * 256 + threadIdx.x;
    if (k < OUTC * HIDD) w2d[k] = (double)W2[k];
}

// ------- gemm1: m1[b][t][c] = sum_e W1[c][e] * emb[feed[b][t]][e] -----------
// block: 256 threads, tile 32t x 256c; register-double-buffered staging
__global__ __launch_bounds__(256)
void gemm1_kernel(const int* __restrict__ feed, const float* __restrict__ emb,
                  const float* __restrict__ W1, double* __restrict__ m1)
{
    __shared__ double wl[GE * WROW];    // [e][c-groups of 8 + pad] 18.4 KB
    __shared__ double xs[GE][GT + 1];   // [e][t] 2.1 KB
    __shared__ int    idxb[GT];

    const int tid = threadIdx.x;
    const int t0  = (blockIdx.x >> 1) * GT;       // 8 t-tiles
    const int c0  = (blockIdx.x & 1) * GC;        // 2 c-tiles
    const int b   = blockIdx.y;

    if (tid < GT) idxb[tid] = feed[b * TT + t0 + tid];
    __syncthreads();

    const int cg = tid & 31;   // c = c0 + 8*cg + j
    const int tg = tid >> 5;   // t = t0 + 4*tg + i
    const int xt = tid >> 3, xe = tid & 7;   // x staging coords

    double acc[4][8];
#pragma unroll
    for (int i = 0; i < 4; ++i)
#pragma unroll
        for (int j = 0; j < 8; ++j) acc[i][j] = 0.0;

    const size_t wrow = (size_t)(c0 + tid) * EMBD;   // this thread's W1 row
    const size_t xrow = (size_t)idxb[xt] * EMBD;

    // ---- preload chunk 0 into registers
    float4 wa = make_float4(0.f, 0.f, 0.f, 0.f);
    float4 wb = make_float4(0.f, 0.f, 0.f, 0.f);
    float  xv = 0.f;
    wa = *(const float4*)&W1[wrow + 0];
    wb = *(const float4*)&W1[wrow + 4];
    xv = emb[xrow + xe];

    const int NCH = (EMBD + GE - 1) / GE;   // 38 (last chunk zero-padded)
    const int g   = (tid >> 3) * WGRP + (tid & 7);

    for (int ch = 0; ch < NCH; ++ch) {
        // ---- commit staged registers for this chunk to LDS
        wl[0 * WROW + g] = (double)wa.x;
        wl[1 * WROW + g] = (double)wa.y;
        wl[2 * WROW + g] = (double)wa.z;
        wl[3 * WROW + g] = (double)wa.w;
        wl[4 * WROW + g] = (double)wb.x;
        wl[5 * WROW + g] = (double)wb.y;
        wl[6 * WROW + g] = (double)wb.z;
        wl[7 * WROW + g] = (double)wb.w;
        xs[xe][xt] = (double)xv;
        __syncthreads();

        // ---- issue next chunk's global loads (fly under the FMAs)
        if (ch + 1 < NCH) {
            const int e0n = (ch + 1) * GE;
            wa = make_float4(0.f, 0.f, 0.f, 0.f);
            wb = make_float4(0.f, 0.f, 0.f, 0.f);
            if (e0n < EMBD)     wa = *(const float4*)&W1[wrow + e0n];
            if (e0n + 4 < EMBD) wb = *(const float4*)&W1[wrow + e0n + 4];
            xv = (e0n + xe < EMBD) ? emb[xrow + e0n + xe] : 0.f;
        }

        // ---- compute this chunk
#pragma unroll
        for (int e = 0; e < GE; ++e) {
            const double* wp = &wl[e * WROW + cg * WGRP];
            const double w0 = wp[0], w1 = wp[1], w2 = wp[2], w3 = wp[3];
            const double w4 = wp[4], w5 = wp[5], w6 = wp[6], w7 = wp[7];
            const double x0 = xs[e][4 * tg + 0];
            const double x1 = xs[e][4 * tg + 1];
            const double x2 = xs[e][4 * tg + 2];
            const double x3 = xs[e][4 * tg + 3];
            acc[0][0] = fma(x0, w0, acc[0][0]); acc[0][1] = fma(x0, w1, acc[0][1]);
            acc[0][2] = fma(x0, w2, acc[0][2]); acc[0][3] = fma(x0, w3, acc[0][3]);
            acc[0][4] = fma(x0, w4, acc[0][4]); acc[0][5] = fma(x0, w5, acc[0][5]);
            acc[0][6] = fma(x0, w6, acc[0][6]); acc[0][7] = fma(x0, w7, acc[0][7]);
            acc[1][0] = fma(x1, w0, acc[1][0]); acc[1][1] = fma(x1, w1, acc[1][1]);
            acc[1][2] = fma(x1, w2, acc[1][2]); acc[1][3] = fma(x1, w3, acc[1][3]);
            acc[1][4] = fma(x1, w4, acc[1][4]); acc[1][5] = fma(x1, w5, acc[1][5]);
            acc[1][6] = fma(x1, w6, acc[1][6]); acc[1][7] = fma(x1, w7, acc[1][7]);
            acc[2][0] = fma(x2, w0, acc[2][0]); acc[2][1] = fma(x2, w1, acc[2][1]);
            acc[2][2] = fma(x2, w2, acc[2][2]); acc[2][3] = fma(x2, w3, acc[2][3]);
            acc[2][4] = fma(x2, w4, acc[2][4]); acc[2][5] = fma(x2, w5, acc[2][5]);
            acc[2][6] = fma(x2, w6, acc[2][6]); acc[2][7] = fma(x2, w7, acc[2][7]);
            acc[3][0] = fma(x3, w0, acc[3][0]); acc[3][1] = fma(x3, w1, acc[3][1]);
            acc[3][2] = fma(x3, w2, acc[3][2]); acc[3][3] = fma(x3, w3, acc[3][3]);
            acc[3][4] = fma(x3, w4, acc[3][4]); acc[3][5] = fma(x3, w5, acc[3][5]);
            acc[3][6] = fma(x3, w6, acc[3][6]); acc[3][7] = fma(x3, w7, acc[3][7]);
        }
        __syncthreads();
    }

    // write m1[b][t][c]
#pragma unroll
    for (int i = 0; i < 4; ++i) {
        double* dst = &m1[((size_t)b * TT + t0 + 4 * tg + i) * HIDD + c0 + 8 * cg];
        *(double2*)(dst + 0) = make_double2(acc[i][0], acc[i][1]);
        *(double2*)(dst + 2) = make_double2(acc[i][2], acc[i][3]);
        *(double2*)(dst + 4) = make_double2(acc[i][4], acc[i][5]);
        *(double2*)(dst + 6) = make_double2(acc[i][6], acc[i][7]);
    }
}

// ------- firscan: psp FIR + spike scan per (b, 16c); m1 is [b][t][c] --------
__global__ __launch_bounds__(256)
void firscan_kernel(const double* __restrict__ m1, const float* __restrict__ srm,
                    const float* __restrict__ refk, unsigned char* __restrict__ s1,
                    int Ks, int Kr)
{
    __shared__ double        h[16 * HSTRD];   // [c][t] 33.0 KB
    __shared__ unsigned char sb[16 * 260];    // spikes, stride 260
    __shared__ double        srm_sm[KSMAX];

    const int tid = threadIdx.x;
    const int c0  = blockIdx.x * 16;
    const int b   = blockIdx.y;

    if (tid < KSMAX) srm_sm[tid] = (tid < Ks) ? (double)srm[tid] : 0.0;

    // stage: m1[b][t][c0..c0+15] -> h[c][t]  (reads coalesced over c)
    for (int u = tid; u < 16 * TT; u += 256) {
        const int c = u & 15, t = u >> 4;
        h[c * HSTRD + t] = m1[((size_t)b * TT + t) * HIDD + c0 + c];
    }
    __syncthreads();

    // FIR: thread (c=tid&15, tb=tid>>4), 16 outputs t = tb*16 + i.
    // 3-bank register window HI/MID/LO, next-LO loaded one block ahead.
    // j ascending 0..KSMAX-1 -> bit-identical to prior rounds.
    const int cf = tid & 15, tb = tid >> 4;
    const int t0 = tb * 16;
    const double* hrow = &h[cf * HSTRD];

    double pout[16];
#pragma unroll
    for (int k = 0; k < 16; ++k) pout[k] = 0.0;

    double HI[8], MID[8], LO[8];
#pragma unroll
    for (int k = 0; k < 8; ++k) {
        HI[k]  = hrow[t0 + 8 + k];
        MID[k] = hrow[t0 + k];
        const int idx = t0 - 8 + k;
        LO[k] = (idx >= 0) ? hrow[idx] : 0.0;
    }

#pragma unroll
    for (int jb = 0; jb < KSMAX; jb += 8) {
        double NEW[8];
        if (jb + 8 < KSMAX) {
#pragma unroll
            for (int k = 0; k < 8; ++k) {
                const int idx = t0 - jb - 16 + k;
                NEW[k] = (idx >= 0) ? hrow[idx] : 0.0;
            }
        }
#pragma unroll
        for (int jj = 0; jj < 8; ++jj) {
            const double sj = srm_sm[jb + jj];
#pragma unroll
            for (int i = 0; i < 16; ++i) {
                const int d = i - jj;    // compile-time after unroll
                const double hv = (d >= 8) ? HI[(d - 8) & 7]
                               : (d >= 0) ? MID[d & 7]
                                          : LO[(8 + d) & 7];
                pout[i] = fma(hv, sj, pout[i]);
            }
        }
        if (jb + 8 < KSMAX) {
#pragma unroll
            for (int k = 0; k < 8; ++k) { HI[k] = MID[k]; MID[k] = LO[k]; LO[k] = NEW[k]; }
        }
    }
    __syncthreads();                 // all FIR reads done before overwrite
#pragma unroll
    for (int k = 0; k < 16; ++k)
        h[cf * HSTRD + t0 + k] = pout[k];
    __syncthreads();

    // spike scan: 16 lanes, one per channel, next-u prefetch
    if (tid < 16) {
        double fut[FUTN], rsh[FUTN];
#pragma unroll
        for (int i = 0; i < FUTN; ++i) {
            fut[i] = (i + 1 < Kr) ? (double)refk[i + 1] : 0.0;
            rsh[i] = 0.0;
        }
        const double*  hr = &h[tid * HSTRD];
        unsigned char* sr = &sb[tid * 260];
        double un = hr[0];
        for (int t = 0; t < TT; ++t) {
            const double uc = un;
            un = (t < TT - 1) ? hr[t + 1] : 0.0;
            const double m  = uc + rsh[0];
            const double sv = (m >= THETA) ? 1.0 : 0.0;
#pragma unroll
            for (int i = 0; i < FUTN - 1; ++i) rsh[i] = fma(sv, fut[i], rsh[i + 1]);
            rsh[FUTN - 1] = sv * fut[FUTN - 1];
            sr[t] = (unsigned char)(sv != 0.0 ? 1 : 0);
        }
    }
    __syncthreads();

    // spikes -> global s1[b][c][t] (uchar via uint, coalesced)
    {
        const int tl2 = tid & 63;
#pragma unroll
        for (int r = 0; r < 4; ++r) {
            const int c = (tid >> 6) + 4 * r;
            const unsigned int v = *(const unsigned int*)&sb[c * 260 + 4 * tl2];
            *(unsigned int*)&s1[((size_t)b * HIDD + c0 + c) * TT + 4 * tl2] = v;
        }
    }
}

// ---------------- layer 2a: m2 = W2 . s1 (f64), parallel over b x t ---------
__global__ __launch_bounds__(256, 2)
void layer2a_kernel(const unsigned char* __restrict__ s1,
                    const double* __restrict__ w2d, double* __restrict__ m2)
{
    __shared__ double w2l[OUTC * HIDD];    // 40 KB
    __shared__ double red[4][OUTC][65];    // 20.8 KB

    const int tid = threadIdx.x;
    const int b = blockIdx.x, q = blockIdx.y;
    const int tl = tid & 63, hq = tid >> 6;
    const int t  = q * 64 + tl;

    for (int u = tid; u < OUTC * HIDD; u += 256) w2l[u] = w2d[u];
    __syncthreads();

    double p[OUTC];
#pragma unroll
    for (int oc = 0; oc < OUTC; ++oc) p[oc] = 0.0;

    const unsigned char* sp = s1 + ((size_t)b * HIDD + hq * 128) * TT + t;
    for (int h0 = 0; h0 < 128; ++h0) {
        const double sv = (double)sp[(size_t)h0 * TT];
        const int hh = hq * 128 + h0;
#pragma unroll
        for (int oc = 0; oc < OUTC; ++oc)
            p[oc] = fma(sv, w2l[oc * HIDD + hh], p[oc]);
    }
#pragma unroll
    for (int oc = 0; oc < OUTC; ++oc) red[hq][oc][tl] = p[oc];
    __syncthreads();

    for (int u = tid; u < OUTC * 64; u += 256) {
        const int oc = u >> 6, t2 = u & 63;
        const double s = ((red[0][oc][t2] + red[1][oc][t2]) +
                          red[2][oc][t2]) + red[3][oc][t2];
        m2[((size_t)b * OUTC + oc) * TT + q * 64 + t2] = s;
    }
}

// ---------------- layer 2b: FIR + spike scan on m2 --------------------------
__global__ __launch_bounds__(256)
void layer2b_kernel(const double* __restrict__ m2, const float* __restrict__ srm,
                    const float* __restrict__ refk, float* __restrict__ out,
                    int Ks, int Kr)
{
    __shared__ double mh[OUTC][257];
    __shared__ double uh[OUTC][257];
    __shared__ double srm_sm[KSMAX];
    __shared__ unsigned char s2[OUTC][260];

    const int tid = threadIdx.x;       // == t
    const int b   = blockIdx.x;

    if (tid < KSMAX) srm_sm[tid] = (tid < Ks) ? (double)srm[tid] : 0.0;
    for (int u = tid; u < OUTC * TT; u += 256)
        mh[u >> 8][u & 255] = m2[(size_t)b * OUTC * TT + u];
    __syncthreads();

    double p[OUTC];
#pragma unroll
    for (int oc = 0; oc < OUTC; ++oc) p[oc] = 0.0;
    for (int j = 0; j < KSMAX; ++j) {
        const int idx = tid - j;
        if (idx >= 0) {
            const double sj = srm_sm[j];
#pragma unroll
            for (int oc = 0; oc < OUTC; ++oc)
                p[oc] = fma(mh[oc][idx], sj, p[oc]);
        }
    }
#pragma unroll
    for (int oc = 0; oc < OUTC; ++oc) uh[oc][tid] = p[oc];
    __syncthreads();

    if (tid < OUTC) {
        double fut[FUTN], rsh[FUTN];
#pragma unroll
        for (int i = 0; i < FUTN; ++i) {
            fut[i] = (i + 1 < Kr) ? (double)refk[i + 1] : 0.0;
            rsh[i] = 0.0;
        }
        for (int t = 0; t < TT; ++t) {
            const double m  = uh[tid][t] + rsh[0];
            const double sv = (m >= THETA) ? 1.0 : 0.0;
#pragma unroll
            for (int i = 0; i < FUTN - 1; ++i) rsh[i] = fma(sv, fut[i], rsh[i + 1]);
            rsh[FUTN - 1] = sv * fut[FUTN - 1];
            s2[tid][t] = (unsigned char)(sv != 0.0 ? 1 : 0);
        }
    }
    __syncthreads();

    for (int u = tid; u < OUTC * TT; u += 256)
        out[(size_t)b * OUTC * TT + u] = (float)s2[u >> 8][u & 255];
}

extern "C" void kernel_launch(void* const* d_in, const int* in_sizes, int n_in,
                              void* d_out, int out_size, void* d_ws, size_t ws_size,
                              hipStream_t stream)
{
    const int*   feed = (const int*)  d_in[0];
    const float* emb  = (const float*)d_in[1];
    const float* W1   = (const float*)d_in[2];
    const float* W2   = (const float*)d_in[3];
    const float* srm  = (const float*)d_in[4];
    const float* refk = (const float*)d_in[5];
    const int Ks = in_sizes[4];
    const int Kr = in_sizes[5];

    // ws layout (proven): [s1 8,388,608][w2d 40,960][m2 1,310,720][m1 67,108,864]
    const size_t S1B  = (size_t)BB * HIDD * TT;
    const size_t W2DB = (size_t)OUTC * HIDD * 8;
    const size_t M2B  = (size_t)BB * OUTC * TT * 8;
    unsigned char* s1c = (unsigned char*)d_ws;
    double* w2d = (double*)((char*)d_ws + S1B);
    double* m2  = (double*)((char*)d_ws + S1B + W2DB);
    double* m1  = (double*)((char*)d_ws + S1B + W2DB + M2B);
    float*  out = (float*)d_out;

    w2cvt_kernel  <<<dim3(20),                      256, 0, stream>>>(W2, w2d);
    gemm1_kernel  <<<dim3((TT / GT) * (HIDD / GC), BB), 256, 0, stream>>>(feed, emb, W1, m1);
    firscan_kernel<<<dim3(HIDD / 16, BB),           256, 0, stream>>>(m1, srm, refk, s1c, Ks, Kr);
    layer2a_kernel<<<dim3(BB, 4),                   256, 0, stream>>>(s1c, w2d, m2);
    layer2b_kernel<<<dim3(BB),                      256, 0, stream>>>(m2, srm, refk, out, Ks, Kr);
}